// Round 1
// baseline (45.876 us; speedup 1.0000x reference)
//
#include <hip/hip_runtime.h>

#define RSURF 50.0f
#define ETA   (1.0f / 1.5f)

__device__ __forceinline__ void refract_one(float ox, float oy, float dx, float dy,
                                            float cx,
                                            float& px, float& py,
                                            float& rx, float& ry) {
    // ray-circle intersection
    float ocx = ox - cx;
    float ocy = oy;              // center y = 0
    float b = dx * ocx + dy * ocy;
    float c = ocx * ocx + ocy * ocy - RSURF * RSURF;
    float disc = fmaxf(b * b - c, 0.0f);
    float t = -b - sqrtf(disc);
    px = ox + t * dx;
    py = oy + t * dy;

    // outward normal, flipped to oppose incoming ray
    float nx = (px - cx) * (1.0f / RSURF);
    float ny = py * (1.0f / RSURF);
    float dot = nx * dx + ny * dy;
    if (dot > 0.0f) { nx = -nx; ny = -ny; }

    // Snell / TIR
    float cosi  = -(nx * dx + ny * dy);
    float sint2 = ETA * ETA * (1.0f - cosi * cosi);
    float cost  = sqrtf(fmaxf(1.0f - sint2, 0.0f));
    if (sint2 > 1.0f) {
        // reflection
        rx = dx + 2.0f * cosi * nx;
        ry = dy + 2.0f * cosi * ny;
    } else {
        float k = ETA * cosi - cost;
        rx = ETA * dx + k * nx;
        ry = ETA * dy + k * ny;
    }
}

__global__ void refractive_surface_kernel(const float4* __restrict__ orig,
                                          const float4* __restrict__ dirs,
                                          const float* __restrict__ tgt,
                                          float4* __restrict__ out_pts,
                                          float4* __restrict__ out_ref,
                                          int nchunks /* = n_rays/2 */,
                                          int n_rays) {
    const float cx = tgt[0] + RSURF;   // circle center x (scalar, L2-broadcast)

    int idx    = blockIdx.x * blockDim.x + threadIdx.x;
    int stride = gridDim.x * blockDim.x;

    for (int i = idx; i < nchunks; i += stride) {
        float4 o = orig[i];   // 2 rays: (o.x,o.y) and (o.z,o.w)
        float4 d = dirs[i];
        float4 p, r;
        refract_one(o.x, o.y, d.x, d.y, cx, p.x, p.y, r.x, r.y);
        refract_one(o.z, o.w, d.z, d.w, cx, p.z, p.w, r.z, r.w);
        out_pts[i] = p;
        out_ref[i] = r;
    }

    // tail ray if n_rays is odd (not hit for N = 8388608, kept for generality)
    if ((n_rays & 1) && idx == 0) {
        int last = n_rays - 1;
        const float* o2 = (const float*)orig;
        const float* d2 = (const float*)dirs;
        float* p2 = (float*)out_pts;
        float* r2 = (float*)out_ref;
        float px, py, rx, ry;
        refract_one(o2[2 * last], o2[2 * last + 1], d2[2 * last], d2[2 * last + 1],
                    cx, px, py, rx, ry);
        p2[2 * last] = px; p2[2 * last + 1] = py;
        r2[2 * last] = rx; r2[2 * last + 1] = ry;
    }
}

extern "C" void kernel_launch(void* const* d_in, const int* in_sizes, int n_in,
                              void* d_out, int out_size, void* d_ws, size_t ws_size,
                              hipStream_t stream) {
    const float4* orig = (const float4*)d_in[0];
    const float4* dirs = (const float4*)d_in[1];
    const float*  tgt  = (const float*)d_in[2];

    int n_rays  = in_sizes[0] / 2;   // in_sizes[0] = N*2 flat floats
    int nchunks = n_rays / 2;        // 2 rays per float4

    float* out = (float*)d_out;
    float4* out_pts = (float4*)out;                        // first N*2 floats
    float4* out_ref = (float4*)(out + 2 * (size_t)n_rays); // next  N*2 floats

    int block = 256;
    int grid  = (nchunks + block - 1) / block;
    if (grid > 2048) grid = 2048;

    refractive_surface_kernel<<<grid, block, 0, stream>>>(
        orig, dirs, tgt, out_pts, out_ref, nchunks, n_rays);
}

// Round 4
// 45.786 us; speedup vs baseline: 1.0020x; 1.0020x over previous
//
#include <hip/hip_runtime.h>

#define RSURF 50.0f
#define ETA   (1.0f / 1.5f)

typedef float f32x4 __attribute__((ext_vector_type(4)));

__device__ __forceinline__ void refract_one(float ox, float oy, float dx, float dy,
                                            float cx,
                                            float& px, float& py,
                                            float& rx, float& ry) {
    // ray-circle intersection
    float ocx = ox - cx;
    float ocy = oy;              // center y = 0
    float b = dx * ocx + dy * ocy;
    float c = ocx * ocx + ocy * ocy - RSURF * RSURF;
    float disc = fmaxf(b * b - c, 0.0f);
    float t = -b - sqrtf(disc);
    px = ox + t * dx;
    py = oy + t * dy;

    // outward normal, flipped to oppose incoming ray
    float nx = (px - cx) * (1.0f / RSURF);
    float ny = py * (1.0f / RSURF);
    float dot = nx * dx + ny * dy;
    if (dot > 0.0f) { nx = -nx; ny = -ny; }

    // Snell / TIR
    float cosi  = -(nx * dx + ny * dy);
    float sint2 = ETA * ETA * (1.0f - cosi * cosi);
    float cost  = sqrtf(fmaxf(1.0f - sint2, 0.0f));
    if (sint2 > 1.0f) {
        // reflection (TIR)
        rx = dx + 2.0f * cosi * nx;
        ry = dy + 2.0f * cosi * ny;
    } else {
        float k = ETA * cosi - cost;
        rx = ETA * dx + k * nx;
        ry = ETA * dy + k * ny;
    }
}

__global__ void refractive_surface_kernel(const f32x4* __restrict__ orig,
                                          const f32x4* __restrict__ dirs,
                                          const float* __restrict__ tgt,
                                          f32x4* __restrict__ out_pts,
                                          f32x4* __restrict__ out_ref,
                                          int nchunks /* = n_rays/2 */,
                                          int n_rays) {
    const float cx = tgt[0] + RSURF;   // circle center x (scalar, L2-broadcast)

    int idx    = blockIdx.x * blockDim.x + threadIdx.x;
    int stride = gridDim.x * blockDim.x;

    for (int i = idx; i < nchunks; i += stride) {
        f32x4 o = orig[i];   // 2 rays: (o.x,o.y) and (o.z,o.w)
        f32x4 d = dirs[i];
        float p0, p1, p2, p3, r0, r1, r2, r3;
        refract_one(o.x, o.y, d.x, d.y, cx, p0, p1, r0, r1);
        refract_one(o.z, o.w, d.z, d.w, cx, p2, p3, r2, r3);
        f32x4 p = {p0, p1, p2, p3};
        f32x4 r = {r0, r1, r2, r3};
        // non-temporal stores: stream outputs to HBM, don't evict the
        // L3-resident inputs (inputs = 134 MB, fit in 256 MiB L3)
        __builtin_nontemporal_store(p, &out_pts[i]);
        __builtin_nontemporal_store(r, &out_ref[i]);
    }

    // tail ray if n_rays is odd (not hit for N = 8388608, kept for generality)
    if ((n_rays & 1) && idx == 0) {
        int last = n_rays - 1;
        const float* o2 = (const float*)orig;
        const float* d2 = (const float*)dirs;
        float* pp = (float*)out_pts;
        float* rr = (float*)out_ref;
        float px, py, rx, ry;
        refract_one(o2[2 * last], o2[2 * last + 1], d2[2 * last], d2[2 * last + 1],
                    cx, px, py, rx, ry);
        pp[2 * last] = px; pp[2 * last + 1] = py;
        rr[2 * last] = rx; rr[2 * last + 1] = ry;
    }
}

extern "C" void kernel_launch(void* const* d_in, const int* in_sizes, int n_in,
                              void* d_out, int out_size, void* d_ws, size_t ws_size,
                              hipStream_t stream) {
    const f32x4* orig = (const f32x4*)d_in[0];
    const f32x4* dirs = (const f32x4*)d_in[1];
    const float* tgt  = (const float*)d_in[2];

    int n_rays  = in_sizes[0] / 2;   // in_sizes[0] = N*2 flat floats
    int nchunks = n_rays / 2;        // 2 rays per float4

    float* out = (float*)d_out;
    f32x4* out_pts = (f32x4*)out;                        // first N*2 floats
    f32x4* out_ref = (f32x4*)(out + 2 * (size_t)n_rays); // next  N*2 floats

    int block = 256;
    int grid  = (nchunks + block - 1) / block;
    if (grid > 2048) grid = 2048;

    refractive_surface_kernel<<<grid, block, 0, stream>>>(
        orig, dirs, tgt, out_pts, out_ref, nchunks, n_rays);
}

// Round 5
// 42.813 us; speedup vs baseline: 1.0715x; 1.0694x over previous
//
#include <hip/hip_runtime.h>

#define RSURF 50.0f
#define ETA   (1.0f / 1.5f)

typedef float f32x4 __attribute__((ext_vector_type(4)));

__device__ __forceinline__ void refract_one(float ox, float oy, float dx, float dy,
                                            float cx,
                                            float& px, float& py,
                                            float& rx, float& ry) {
    // ray-circle intersection
    float ocx = ox - cx;
    float ocy = oy;              // center y = 0
    float b = dx * ocx + dy * ocy;
    float c = ocx * ocx + ocy * ocy - RSURF * RSURF;
    float disc = fmaxf(b * b - c, 0.0f);
    float t = -b - sqrtf(disc);
    px = ox + t * dx;
    py = oy + t * dy;

    // outward normal, flipped to oppose incoming ray
    float nx = (px - cx) * (1.0f / RSURF);
    float ny = py * (1.0f / RSURF);
    float dot = nx * dx + ny * dy;
    if (dot > 0.0f) { nx = -nx; ny = -ny; }

    // Snell / TIR
    float cosi  = -(nx * dx + ny * dy);
    float sint2 = ETA * ETA * (1.0f - cosi * cosi);
    float cost  = sqrtf(fmaxf(1.0f - sint2, 0.0f));
    if (sint2 > 1.0f) {
        // reflection (TIR)
        rx = dx + 2.0f * cosi * nx;
        ry = dy + 2.0f * cosi * ny;
    } else {
        float k = ETA * cosi - cost;
        rx = ETA * dx + k * nx;
        ry = ETA * dy + k * ny;
    }
}

// One chunk (2 rays, one float4 of origins + one of dirs) per thread:
// max TLP, no loop-carried serialization — discriminates latency-bound
// vs bandwidth-bound.
__global__ void refractive_surface_kernel(const f32x4* __restrict__ orig,
                                          const f32x4* __restrict__ dirs,
                                          const float* __restrict__ tgt,
                                          f32x4* __restrict__ out_pts,
                                          f32x4* __restrict__ out_ref,
                                          int nchunks /* = n_rays/2 */,
                                          int n_rays) {
    const float cx = tgt[0] + RSURF;   // circle center x (scalar, L2-broadcast)

    int i = blockIdx.x * blockDim.x + threadIdx.x;
    if (i < nchunks) {
        f32x4 o = orig[i];   // 2 rays: (o.x,o.y) and (o.z,o.w)
        f32x4 d = dirs[i];
        float p0, p1, p2, p3, r0, r1, r2, r3;
        refract_one(o.x, o.y, d.x, d.y, cx, p0, p1, r0, r1);
        refract_one(o.z, o.w, d.z, d.w, cx, p2, p3, r2, r3);
        f32x4 p = {p0, p1, p2, p3};
        f32x4 r = {r0, r1, r2, r3};
        __builtin_nontemporal_store(p, &out_pts[i]);
        __builtin_nontemporal_store(r, &out_ref[i]);
    }

    // tail ray if n_rays is odd (not hit for N = 8388608, kept for generality)
    if ((n_rays & 1) && i == 0) {
        int last = n_rays - 1;
        const float* o2 = (const float*)orig;
        const float* d2 = (const float*)dirs;
        float* pp = (float*)out_pts;
        float* rr = (float*)out_ref;
        float px, py, rx, ry;
        refract_one(o2[2 * last], o2[2 * last + 1], d2[2 * last], d2[2 * last + 1],
                    cx, px, py, rx, ry);
        pp[2 * last] = px; pp[2 * last + 1] = py;
        rr[2 * last] = rx; rr[2 * last + 1] = ry;
    }
}

extern "C" void kernel_launch(void* const* d_in, const int* in_sizes, int n_in,
                              void* d_out, int out_size, void* d_ws, size_t ws_size,
                              hipStream_t stream) {
    const f32x4* orig = (const f32x4*)d_in[0];
    const f32x4* dirs = (const f32x4*)d_in[1];
    const float* tgt  = (const float*)d_in[2];

    int n_rays  = in_sizes[0] / 2;   // in_sizes[0] = N*2 flat floats
    int nchunks = n_rays / 2;        // 2 rays per float4

    float* out = (float*)d_out;
    f32x4* out_pts = (f32x4*)out;                        // first N*2 floats
    f32x4* out_ref = (f32x4*)(out + 2 * (size_t)n_rays); // next  N*2 floats

    int block = 256;
    int grid  = (nchunks + block - 1) / block;           // exact grid: 16384 blocks

    refractive_surface_kernel<<<grid, block, 0, stream>>>(
        orig, dirs, tgt, out_pts, out_ref, nchunks, n_rays);
}